// Round 1
// baseline (5792.332 us; speedup 1.0000x reference)
//
#include <hip/hip_runtime.h>
#include <hip/hip_bf16.h>

#define BB 512
#define TT 1024
#define CIN 128
#define HH 64
#define GG 256  // 4*H

__device__ __forceinline__ float sigf(float x) { return 1.0f / (1.0f + __expf(-x)); }
__device__ __forceinline__ float tanhfast(float x) { return 2.0f / (1.0f + __expf(-2.0f * x)) - 1.0f; }

// ---------------- Layer 1: fused bidirectional scan ----------------
// grid (128, 2): blockIdx.x = batch group (4 rows), blockIdx.y = direction.
// 256 threads = one per gate. Weights live in registers (unrolled float4 arrays).
__global__ __launch_bounds__(256, 1)
void lstm_l1(const float* __restrict__ x, const float* __restrict__ w_ih,
             const float* __restrict__ w_hh, const float* __restrict__ b_ih,
             const float* __restrict__ b_hh, __hip_bfloat16* __restrict__ out1)
{
    const int d  = blockIdx.y;
    const int b0 = blockIdx.x * 4;
    const int g  = threadIdx.x;

    __shared__ float x_s[4][CIN];
    __shared__ float h_s[4][HH];
    __shared__ float gpre[4][GG];

    // register-resident weights for this gate row
    float4 wih[32];
    const float4* wp = (const float4*)(w_ih + ((size_t)(d * GG + g)) * CIN);
    #pragma unroll
    for (int k = 0; k < 32; ++k) wih[k] = wp[k];
    float4 whh[16];
    const float4* hp = (const float4*)(w_hh + ((size_t)(d * GG + g)) * HH);
    #pragma unroll
    for (int k = 0; k < 16; ++k) whh[k] = hp[k];
    const float bias = b_ih[d * GG + g] + b_hh[d * GG + g];

    const int cr = g >> 6, cj = g & 63;  // cell ownership: (row, hidden j)
    float c = 0.0f;
    h_s[cr][cj] = 0.0f;  // 256 threads cover 4x64

    for (int tt = 0; tt < TT; ++tt) {
        const int t = d ? (TT - 1 - tt) : tt;
        // stage x_t: thread -> (row = g>>6, pos = g&63), 2 floats each (coalesced)
        {
            const int r = g >> 6, pos = g & 63;
            const float2 v = *(const float2*)(x + (((size_t)(b0 + r)) * TT + t) * CIN + pos * 2);
            x_s[r][pos * 2]     = v.x;
            x_s[r][pos * 2 + 1] = v.y;
        }
        __syncthreads();  // x_s ready; h_s (from prev step / init) visible

        float a0 = bias, a1 = bias, a2 = bias, a3 = bias;
        const float4* xs0 = (const float4*)x_s[0];
        const float4* xs1 = (const float4*)x_s[1];
        const float4* xs2 = (const float4*)x_s[2];
        const float4* xs3 = (const float4*)x_s[3];
        #pragma unroll
        for (int k = 0; k < 32; ++k) {
            const float4 w = wih[k];
            float4 v;
            v = xs0[k]; a0 = fmaf(w.x, v.x, a0); a0 = fmaf(w.y, v.y, a0); a0 = fmaf(w.z, v.z, a0); a0 = fmaf(w.w, v.w, a0);
            v = xs1[k]; a1 = fmaf(w.x, v.x, a1); a1 = fmaf(w.y, v.y, a1); a1 = fmaf(w.z, v.z, a1); a1 = fmaf(w.w, v.w, a1);
            v = xs2[k]; a2 = fmaf(w.x, v.x, a2); a2 = fmaf(w.y, v.y, a2); a2 = fmaf(w.z, v.z, a2); a2 = fmaf(w.w, v.w, a2);
            v = xs3[k]; a3 = fmaf(w.x, v.x, a3); a3 = fmaf(w.y, v.y, a3); a3 = fmaf(w.z, v.z, a3); a3 = fmaf(w.w, v.w, a3);
        }
        const float4* hs0 = (const float4*)h_s[0];
        const float4* hs1 = (const float4*)h_s[1];
        const float4* hs2 = (const float4*)h_s[2];
        const float4* hs3 = (const float4*)h_s[3];
        #pragma unroll
        for (int k = 0; k < 16; ++k) {
            const float4 w = whh[k];
            float4 v;
            v = hs0[k]; a0 = fmaf(w.x, v.x, a0); a0 = fmaf(w.y, v.y, a0); a0 = fmaf(w.z, v.z, a0); a0 = fmaf(w.w, v.w, a0);
            v = hs1[k]; a1 = fmaf(w.x, v.x, a1); a1 = fmaf(w.y, v.y, a1); a1 = fmaf(w.z, v.z, a1); a1 = fmaf(w.w, v.w, a1);
            v = hs2[k]; a2 = fmaf(w.x, v.x, a2); a2 = fmaf(w.y, v.y, a2); a2 = fmaf(w.z, v.z, a2); a2 = fmaf(w.w, v.w, a2);
            v = hs3[k]; a3 = fmaf(w.x, v.x, a3); a3 = fmaf(w.y, v.y, a3); a3 = fmaf(w.z, v.z, a3); a3 = fmaf(w.w, v.w, a3);
        }
        gpre[0][g] = a0; gpre[1][g] = a1; gpre[2][g] = a2; gpre[3][g] = a3;
        __syncthreads();  // gpre ready; all x_s/h_s reads done

        // cell update (thread owns (cr, cj); c stays in a register)
        {
            const float i  = sigf(gpre[cr][cj]);
            const float f  = sigf(gpre[cr][64 + cj]);
            const float gg = tanhfast(gpre[cr][128 + cj]);
            const float o  = sigf(gpre[cr][192 + cj]);
            c = f * c + i * gg;
            const float h = o * tanhfast(c);
            h_s[cr][cj] = h;
            out1[(((size_t)(b0 + cr)) * TT + t) * CIN + d * HH + cj] = __float2bfloat16(h);
        }
    }
}

// ---------------- Layer 2 forward: full scan, keep only final h ----------------
// grid 256: 2 rows per block; input is layer-1 output (bf16, 128 channels).
__global__ __launch_bounds__(256, 1)
void lstm_l2_fwd(const __hip_bfloat16* __restrict__ in, const float* __restrict__ w_ih,
                 const float* __restrict__ w_hh, const float* __restrict__ b_ih,
                 const float* __restrict__ b_hh, float* __restrict__ hlast)
{
    const int b0 = blockIdx.x * 2;
    const int g  = threadIdx.x;

    __shared__ float x_s[2][CIN];
    __shared__ float h_s[2][HH];
    __shared__ float gpre[2][GG];

    float4 wih[32];
    const float4* wp = (const float4*)(w_ih + ((size_t)(2 * GG + g)) * CIN);  // l=1, d=0
    #pragma unroll
    for (int k = 0; k < 32; ++k) wih[k] = wp[k];
    float4 whh[16];
    const float4* hp = (const float4*)(w_hh + ((size_t)(2 * GG + g)) * HH);
    #pragma unroll
    for (int k = 0; k < 16; ++k) whh[k] = hp[k];
    const float bias = b_ih[2 * GG + g] + b_hh[2 * GG + g];

    const int cr = g >> 6, cj = g & 63;  // valid for g < 128
    float c = 0.0f, hloc = 0.0f;
    if (g < 128) h_s[cr][cj] = 0.0f;

    for (int t = 0; t < TT; ++t) {
        // stage input row: thread -> (row = g>>7, pos = g&127)
        {
            const int r = g >> 7, pos = g & 127;
            x_s[r][pos] = __bfloat162float(in[(((size_t)(b0 + r)) * TT + t) * CIN + pos]);
        }
        __syncthreads();

        float a0 = bias, a1 = bias;
        const float4* xs0 = (const float4*)x_s[0];
        const float4* xs1 = (const float4*)x_s[1];
        #pragma unroll
        for (int k = 0; k < 32; ++k) {
            const float4 w = wih[k];
            float4 v;
            v = xs0[k]; a0 = fmaf(w.x, v.x, a0); a0 = fmaf(w.y, v.y, a0); a0 = fmaf(w.z, v.z, a0); a0 = fmaf(w.w, v.w, a0);
            v = xs1[k]; a1 = fmaf(w.x, v.x, a1); a1 = fmaf(w.y, v.y, a1); a1 = fmaf(w.z, v.z, a1); a1 = fmaf(w.w, v.w, a1);
        }
        const float4* hs0 = (const float4*)h_s[0];
        const float4* hs1 = (const float4*)h_s[1];
        #pragma unroll
        for (int k = 0; k < 16; ++k) {
            const float4 w = whh[k];
            float4 v;
            v = hs0[k]; a0 = fmaf(w.x, v.x, a0); a0 = fmaf(w.y, v.y, a0); a0 = fmaf(w.z, v.z, a0); a0 = fmaf(w.w, v.w, a0);
            v = hs1[k]; a1 = fmaf(w.x, v.x, a1); a1 = fmaf(w.y, v.y, a1); a1 = fmaf(w.z, v.z, a1); a1 = fmaf(w.w, v.w, a1);
        }
        gpre[0][g] = a0; gpre[1][g] = a1;
        __syncthreads();

        if (g < 128) {
            const float i  = sigf(gpre[cr][cj]);
            const float f  = sigf(gpre[cr][64 + cj]);
            const float gg = tanhfast(gpre[cr][128 + cj]);
            const float o  = sigf(gpre[cr][192 + cj]);
            c = f * c + i * gg;
            hloc = o * tanhfast(c);
            h_s[cr][cj] = hloc;
        }
    }
    if (g < 128) hlast[(size_t)(b0 + cr) * HH + cj] = hloc;
}

// ---------------- Layer 2 backward (single step from zero state) + FC ----------------
// grid 512: one block per batch row.
__global__ __launch_bounds__(256, 1)
void lstm_l2_bwd_fc(const __hip_bfloat16* __restrict__ in, const float* __restrict__ w_ih,
                    const float* __restrict__ b_ih, const float* __restrict__ b_hh,
                    const float* __restrict__ hlast, const float* __restrict__ fc_w,
                    const float* __restrict__ fc_b, float* __restrict__ out)
{
    const int b = blockIdx.x;
    const int g = threadIdx.x;
    __shared__ float gpre[GG];
    __shared__ float hb[HH];

    // h=0 at the first reverse step => only W_ih @ x + bias matters
    float acc = b_ih[3 * GG + g] + b_hh[3 * GG + g];  // l=1, d=1
    const float* wp = w_ih + ((size_t)(3 * GG + g)) * CIN;
    const __hip_bfloat16* xp = in + ((size_t)b * TT + (TT - 1)) * CIN;
    #pragma unroll 8
    for (int k = 0; k < CIN; ++k) acc = fmaf(wp[k], __bfloat162float(xp[k]), acc);
    gpre[g] = acc;
    __syncthreads();

    if (g < HH) {
        const float i  = sigf(gpre[g]);
        const float gg = tanhfast(gpre[128 + g]);
        const float o  = sigf(gpre[192 + g]);
        const float c  = i * gg;  // f * 0 + i * gg
        hb[g] = o * tanhfast(c);
    }
    __syncthreads();

    if (g < HH) {
        float p = fc_w[g] * hlast[(size_t)b * HH + g] + fc_w[HH + g] * hb[g];
        #pragma unroll
        for (int off = 32; off > 0; off >>= 1) p += __shfl_down(p, off);
        if (g == 0) out[b] = p + fc_b[0];
    }
}

extern "C" void kernel_launch(void* const* d_in, const int* in_sizes, int n_in,
                              void* d_out, int out_size, void* d_ws, size_t ws_size,
                              hipStream_t stream)
{
    const float* x    = (const float*)d_in[0];
    const float* w_ih = (const float*)d_in[1];
    const float* w_hh = (const float*)d_in[2];
    const float* b_ih = (const float*)d_in[3];
    const float* b_hh = (const float*)d_in[4];
    const float* fc_w = (const float*)d_in[5];
    const float* fc_b = (const float*)d_in[6];
    float* out = (float*)d_out;

    // workspace: [ out1: B*T*128 bf16 = 128 MiB ][ hlast: B*64 f32 = 128 KiB ]
    __hip_bfloat16* out1 = (__hip_bfloat16*)d_ws;
    float* hlast = (float*)((char*)d_ws + (size_t)BB * TT * CIN * sizeof(__hip_bfloat16));

    lstm_l1<<<dim3(128, 2), 256, 0, stream>>>(x, w_ih, w_hh, b_ih, b_hh, out1);
    lstm_l2_fwd<<<dim3(256), 256, 0, stream>>>(out1, w_ih, w_hh, b_ih, b_hh, hlast);
    lstm_l2_bwd_fc<<<dim3(512), 256, 0, stream>>>(out1, w_ih, b_ih, b_hh, hlast, fc_w, fc_b, out);
}

// Round 2
// 2380.036 us; speedup vs baseline: 2.4337x; 2.4337x over previous
//
#include <hip/hip_runtime.h>
#include <hip/hip_bf16.h>

#define TT 1024
#define BB 512

typedef _Float16 half_t;
typedef __attribute__((ext_vector_type(8))) _Float16 v8h;
typedef __attribute__((ext_vector_type(4))) float v4f;

__device__ __forceinline__ float sigf(float x) { return 1.0f / (1.0f + __expf(-x)); }
__device__ __forceinline__ float tanhfast(float x) { return 2.0f / (1.0f + __expf(-2.0f * x)) - 1.0f; }

// Unified LSTM scan kernel.
// R rows per block (M rows of the MFMA tile used). 256 threads = 4 waves.
// Wave w owns gate columns {gt*64 + w*16 + n : gt in 0..3, n in 0..15}, so the
// cell update for hidden j = w*16+n is per-lane local on the C fragments
// (C layout: col = lane&15, row = (lane>>4)*4 + reg).
// Gates = [x_t | h_{t-1}] @ [W_ih | W_hh]^T via v_mfma_f32_16x16x32_f16:
// K tiles 0..3 = x (128 ch), tiles 4..5 = h (64).
template<int R, bool IN_F32, bool WRITE_SEQ, bool WRITE_LAST>
__global__ __launch_bounds__(256, 2)
void lstm_scan(const void* __restrict__ in_v, const float* __restrict__ w_ih,
               const float* __restrict__ w_hh, const float* __restrict__ b_ih,
               const float* __restrict__ b_hh, int layer, int use_grid_dir,
               half_t* __restrict__ out_seq, float* __restrict__ out_last)
{
    const int dir = use_grid_dir ? blockIdx.y : 0;
    const int rev = dir;                 // dir 1 == reverse scan
    const int wrow = layer * 2 + dir;    // weight row block
    const int col_off = dir * 64;        // out_seq channel offset

    const int b0  = blockIdx.x * R;
    const int wv  = threadIdx.x >> 6;
    const int l   = threadIdx.x & 63;
    const int q   = l >> 4;              // lane quad group
    const int n16 = l & 15;              // col within 16-wide tile / row m for A
    const int j   = wv * 16 + n16;       // hidden index owned by this lane
    const bool xlane = (n16 < R);        // lanes holding valid A rows

    __shared__ __align__(16) half_t hs[R][64];
    if ((int)threadIdx.x < R * 64) ((half_t*)hs)[threadIdx.x] = (half_t)0.f;

    // ---- weight B-fragments (registers): B[k][n] = W[gate gidx(n)][k] ----
    // lane: n = n16, k = kt*32 + q*8 + jj
    v8h wb[4][6];
    float bias[4];
    #pragma unroll
    for (int gt = 0; gt < 4; ++gt) {
        const int gidx = gt * 64 + j;
        const size_t grow = (size_t)(wrow * 256 + gidx);
        const float* pih = w_ih + grow * 128 + q * 8;
        #pragma unroll
        for (int kt = 0; kt < 4; ++kt) {
            const float4 a = *(const float4*)(pih + kt * 32);
            const float4 b = *(const float4*)(pih + kt * 32 + 4);
            v8h f;
            f[0] = (half_t)a.x; f[1] = (half_t)a.y; f[2] = (half_t)a.z; f[3] = (half_t)a.w;
            f[4] = (half_t)b.x; f[5] = (half_t)b.y; f[6] = (half_t)b.z; f[7] = (half_t)b.w;
            wb[gt][kt] = f;
        }
        const float* phh = w_hh + grow * 64 + q * 8;
        #pragma unroll
        for (int kt = 0; kt < 2; ++kt) {
            const float4 a = *(const float4*)(phh + kt * 32);
            const float4 b = *(const float4*)(phh + kt * 32 + 4);
            v8h f;
            f[0] = (half_t)a.x; f[1] = (half_t)a.y; f[2] = (half_t)a.z; f[3] = (half_t)a.w;
            f[4] = (half_t)b.x; f[5] = (half_t)b.y; f[6] = (half_t)b.z; f[7] = (half_t)b.w;
            wb[gt][4 + kt] = f;
        }
        bias[gt] = b_ih[grow] + b_hh[grow];
    }

    float c[R], hcur[R];
    #pragma unroll
    for (int r = 0; r < R; ++r) { c[r] = 0.f; hcur[r] = 0.f; }

    // ---- x fragment prologue (time tt=0) ----
    float4 xr[4][2];     // raw fp32 staging (IN_F32 path)
    v8h    xn[4];        // raw fp16 staging
    v8h    xf[4];        // current-step A fragments
    #pragma unroll
    for (int kt = 0; kt < 4; ++kt) {
        #pragma unroll
        for (int e = 0; e < 8; ++e) xf[kt][e] = (half_t)0.f;
        xn[kt] = xf[kt];
    }
    {
        const int t0 = rev ? (TT - 1) : 0;
        if (xlane) {
            if constexpr (IN_F32) {
                const float* xp = (const float*)in_v + (((size_t)(b0 + n16)) * TT + t0) * 128 + q * 8;
                #pragma unroll
                for (int kt = 0; kt < 4; ++kt) {
                    xr[kt][0] = *(const float4*)(xp + kt * 32);
                    xr[kt][1] = *(const float4*)(xp + kt * 32 + 4);
                }
            } else {
                const half_t* xp = (const half_t*)in_v + (((size_t)(b0 + n16)) * TT + t0) * 128 + q * 8;
                #pragma unroll
                for (int kt = 0; kt < 4; ++kt) xn[kt] = *(const v8h*)(xp + kt * 32);
            }
        }
        // convert prologue fragments
        if (xlane) {
            if constexpr (IN_F32) {
                #pragma unroll
                for (int kt = 0; kt < 4; ++kt) {
                    v8h f;
                    f[0] = (half_t)xr[kt][0].x; f[1] = (half_t)xr[kt][0].y;
                    f[2] = (half_t)xr[kt][0].z; f[3] = (half_t)xr[kt][0].w;
                    f[4] = (half_t)xr[kt][1].x; f[5] = (half_t)xr[kt][1].y;
                    f[6] = (half_t)xr[kt][1].z; f[7] = (half_t)xr[kt][1].w;
                    xf[kt] = f;
                }
            } else {
                #pragma unroll
                for (int kt = 0; kt < 4; ++kt) xf[kt] = xn[kt];
            }
        }
    }
    __syncthreads();   // hs zero-init visible

    for (int tt = 0; tt < TT; ++tt) {
        const int t = rev ? (TT - 1 - tt) : tt;

        // ---- prefetch next step's x (no recurrence dependency) ----
        if (tt + 1 < TT && xlane) {
            const int tn = rev ? (TT - 2 - tt) : (tt + 1);
            if constexpr (IN_F32) {
                const float* xp = (const float*)in_v + (((size_t)(b0 + n16)) * TT + tn) * 128 + q * 8;
                #pragma unroll
                for (int kt = 0; kt < 4; ++kt) {
                    xr[kt][0] = *(const float4*)(xp + kt * 32);
                    xr[kt][1] = *(const float4*)(xp + kt * 32 + 4);
                }
            } else {
                const half_t* xp = (const half_t*)in_v + (((size_t)(b0 + n16)) * TT + tn) * 128 + q * 8;
                #pragma unroll
                for (int kt = 0; kt < 4; ++kt) xn[kt] = *(const v8h*)(xp + kt * 32);
            }
        }

        // ---- h fragments from LDS (A layout: m = n16, k = kh*32 + q*8 + jj) ----
        v8h hf0, hf1;
        #pragma unroll
        for (int e = 0; e < 8; ++e) { hf0[e] = (half_t)0.f; hf1[e] = (half_t)0.f; }
        if (xlane) {
            hf0 = *(const v8h*)&hs[n16][q * 8];
            hf1 = *(const v8h*)&hs[n16][32 + q * 8];
        }

        // ---- MFMA: 4 gate-subtile chains x 6 K-tiles ----
        v4f acc[4];
        #pragma unroll
        for (int gt = 0; gt < 4; ++gt) {
            v4f a = {bias[gt], bias[gt], bias[gt], bias[gt]};
            a = __builtin_amdgcn_mfma_f32_16x16x32_f16(xf[0], wb[gt][0], a, 0, 0, 0);
            a = __builtin_amdgcn_mfma_f32_16x16x32_f16(xf[1], wb[gt][1], a, 0, 0, 0);
            a = __builtin_amdgcn_mfma_f32_16x16x32_f16(xf[2], wb[gt][2], a, 0, 0, 0);
            a = __builtin_amdgcn_mfma_f32_16x16x32_f16(xf[3], wb[gt][3], a, 0, 0, 0);
            a = __builtin_amdgcn_mfma_f32_16x16x32_f16(hf0,   wb[gt][4], a, 0, 0, 0);
            a = __builtin_amdgcn_mfma_f32_16x16x32_f16(hf1,   wb[gt][5], a, 0, 0, 0);
            acc[gt] = a;
        }

        // ---- cell update: rows 0..R-1 live on lane group q==0, reg index r ----
        if (q == 0) {
            #pragma unroll
            for (int r = 0; r < R; ++r) {
                const float iv = sigf(acc[0][r]);
                const float fv = sigf(acc[1][r]);
                const float gv = tanhfast(acc[2][r]);
                const float ov = sigf(acc[3][r]);
                c[r] = fv * c[r] + iv * gv;
                hcur[r] = ov * tanhfast(c[r]);
            }
        }
        __syncthreads();   // (a) all hf LDS reads consumed before overwrite

        if (q == 0) {
            #pragma unroll
            for (int r = 0; r < R; ++r) {
                hs[r][j] = (half_t)hcur[r];
                if constexpr (WRITE_SEQ) {
                    out_seq[(((size_t)(b0 + r)) * TT + t) * 128 + col_off + j] = (half_t)hcur[r];
                }
            }
        }

        // ---- convert prefetched x for next step ----
        if (tt + 1 < TT && xlane) {
            if constexpr (IN_F32) {
                #pragma unroll
                for (int kt = 0; kt < 4; ++kt) {
                    v8h f;
                    f[0] = (half_t)xr[kt][0].x; f[1] = (half_t)xr[kt][0].y;
                    f[2] = (half_t)xr[kt][0].z; f[3] = (half_t)xr[kt][0].w;
                    f[4] = (half_t)xr[kt][1].x; f[5] = (half_t)xr[kt][1].y;
                    f[6] = (half_t)xr[kt][1].z; f[7] = (half_t)xr[kt][1].w;
                    xf[kt] = f;
                }
            } else {
                #pragma unroll
                for (int kt = 0; kt < 4; ++kt) xf[kt] = xn[kt];
            }
        }
        __syncthreads();   // (b) new h visible to all waves
    }

    if constexpr (WRITE_LAST) {
        if (q == 0) {
            #pragma unroll
            for (int r = 0; r < R; ++r) out_last[((size_t)(b0 + r)) * 64 + j] = hcur[r];
        }
    }
}

// ---------------- Layer 2 backward (single step from zero state) + FC ----------------
__global__ __launch_bounds__(256)
void l2bwd_fc(const half_t* __restrict__ in, const float* __restrict__ w_ih,
              const float* __restrict__ b_ih, const float* __restrict__ b_hh,
              const float* __restrict__ hlast, const float* __restrict__ fc_w,
              const float* __restrict__ fc_b, float* __restrict__ out)
{
    const int b = blockIdx.x;
    const int g = threadIdx.x;
    __shared__ float gpre[256];
    __shared__ float hb[64];

    // h=0 at the first reverse step => only W_ih @ x + bias matters
    float acc = b_ih[3 * 256 + g] + b_hh[3 * 256 + g];
    const float* wp = w_ih + ((size_t)(3 * 256 + g)) * 128;
    const half_t* xp = in + ((size_t)b * TT + (TT - 1)) * 128;
    #pragma unroll
    for (int k = 0; k < 128; k += 8) {
        const float4 w0 = *(const float4*)(wp + k);
        const float4 w1 = *(const float4*)(wp + k + 4);
        const v8h xv = *(const v8h*)(xp + k);
        acc = fmaf(w0.x, (float)xv[0], acc); acc = fmaf(w0.y, (float)xv[1], acc);
        acc = fmaf(w0.z, (float)xv[2], acc); acc = fmaf(w0.w, (float)xv[3], acc);
        acc = fmaf(w1.x, (float)xv[4], acc); acc = fmaf(w1.y, (float)xv[5], acc);
        acc = fmaf(w1.z, (float)xv[6], acc); acc = fmaf(w1.w, (float)xv[7], acc);
    }
    gpre[g] = acc;
    __syncthreads();

    if (g < 64) {
        const float i  = sigf(gpre[g]);
        const float gg = tanhfast(gpre[128 + g]);
        const float o  = sigf(gpre[192 + g]);
        const float cc = i * gg;   // f * 0 + i * g
        hb[g] = o * tanhfast(cc);
    }
    __syncthreads();

    if (g < 64) {
        float p = fc_w[g] * hlast[(size_t)b * 64 + g] + fc_w[64 + g] * hb[g];
        #pragma unroll
        for (int off = 32; off > 0; off >>= 1) p += __shfl_down(p, off);
        if (g == 0) out[b] = p + fc_b[0];
    }
}

extern "C" void kernel_launch(void* const* d_in, const int* in_sizes, int n_in,
                              void* d_out, int out_size, void* d_ws, size_t ws_size,
                              hipStream_t stream)
{
    const float* x    = (const float*)d_in[0];
    const float* w_ih = (const float*)d_in[1];
    const float* w_hh = (const float*)d_in[2];
    const float* b_ih = (const float*)d_in[3];
    const float* b_hh = (const float*)d_in[4];
    const float* fc_w = (const float*)d_in[5];
    const float* fc_b = (const float*)d_in[6];
    float* out = (float*)d_out;

    // workspace: [ out1: B*T*128 fp16 = 128 MiB ][ hlast: B*64 f32 = 128 KiB ]
    half_t* out1 = (half_t*)d_ws;
    float* hlast = (float*)((char*)d_ws + (size_t)BB * TT * 128 * sizeof(half_t));

    // Layer 1: both directions, R=2 rows/block -> 512 blocks (2 blocks/CU)
    lstm_scan<2, true, true, false><<<dim3(BB / 2, 2), 256, 0, stream>>>(
        x, w_ih, w_hh, b_ih, b_hh, 0, 1, out1, nullptr);

    // Layer 2 forward: R=1 -> 512 blocks (2 blocks/CU), keep only final h
    lstm_scan<1, false, false, true><<<dim3(BB, 1), 256, 0, stream>>>(
        out1, w_ih, w_hh, b_ih, b_hh, 1, 0, nullptr, hlast);

    // Layer 2 backward single step + FC
    l2bwd_fc<<<BB, 256, 0, stream>>>(out1, w_ih, b_ih, b_hh, hlast, fc_w, fc_b, out);
}

// Round 3
// 1981.222 us; speedup vs baseline: 2.9236x; 1.2013x over previous
//
#include <hip/hip_runtime.h>
#include <hip/hip_bf16.h>

#define TT 1024
#define BB 512

typedef _Float16 half_t;
typedef __attribute__((ext_vector_type(8))) _Float16 v8h;
typedef __attribute__((ext_vector_type(4))) float v4f;

__device__ __forceinline__ float sigf(float x) { return 1.0f / (1.0f + __expf(-x)); }
__device__ __forceinline__ float tanhfast(float x) { return 2.0f / (1.0f + __expf(-2.0f * x)) - 1.0f; }

// Barrier that drains ONLY lgkmcnt (LDS) — leaves global loads/stores in
// flight across the barrier. __syncthreads() would s_waitcnt vmcnt(0) and put
// the ~900-cycle HBM prefetch latency on the recurrence critical path.
__device__ __forceinline__ void barrier_lds_only() {
    asm volatile("s_waitcnt lgkmcnt(0)\n\ts_barrier" ::: "memory");
}

// Unified LSTM scan. R batch rows/block (M rows of the 16x16x32 tile used).
// 256 threads = 4 waves; wave wv owns gate columns {gt*64 + wv*16 + n16}.
// C layout: col = lane&15, row = (lane>>4)*4 + reg  => cell update for batch
// rows 0..R-1 (R<=4) is per-lane local on lanes q==0, reg index r.
// h_{t-1} double-buffered in LDS: read hs[tt&1], write hs[(tt&1)^1],
// one lds-only barrier per step.
template<int R, bool IN_F32, bool WRITE_SEQ, bool WRITE_LAST>
__global__ __launch_bounds__(256, 2)
void lstm_scan(const void* __restrict__ in_v, const float* __restrict__ w_ih,
               const float* __restrict__ w_hh, const float* __restrict__ b_ih,
               const float* __restrict__ b_hh, int layer, int use_grid_dir,
               half_t* __restrict__ out_seq, float* __restrict__ out_last)
{
    const int dir = use_grid_dir ? blockIdx.y : 0;
    const int rev = dir;
    const int wrow = layer * 2 + dir;
    const int col_off = dir * 64;

    const int b0  = blockIdx.x * R;
    const int wv  = threadIdx.x >> 6;
    const int l   = threadIdx.x & 63;
    const int q   = l >> 4;
    const int n16 = l & 15;
    const int j   = wv * 16 + n16;
    const int rowc = (n16 < R) ? n16 : (R - 1);  // clamped row: all lanes load valid addrs

    __shared__ __align__(16) half_t hs[2][16][64];  // 4 KB, rows >= R stay zero
    {
        v8h z;
        #pragma unroll
        for (int e = 0; e < 8; ++e) z[e] = (half_t)0.f;
        ((v8h*)hs)[threadIdx.x] = z;  // 256 * 16B = 4 KB
    }

    // ---- weight B-fragments (registers): B[k][n] = W[gate gt*64+j][k] ----
    v8h wb[4][6];
    float bias[4];
    #pragma unroll
    for (int gt = 0; gt < 4; ++gt) {
        const size_t grow = (size_t)(wrow * 256 + gt * 64 + j);
        const float* pih = w_ih + grow * 128 + q * 8;
        #pragma unroll
        for (int kt = 0; kt < 4; ++kt) {
            const float4 a = *(const float4*)(pih + kt * 32);
            const float4 b = *(const float4*)(pih + kt * 32 + 4);
            v8h f;
            f[0] = (half_t)a.x; f[1] = (half_t)a.y; f[2] = (half_t)a.z; f[3] = (half_t)a.w;
            f[4] = (half_t)b.x; f[5] = (half_t)b.y; f[6] = (half_t)b.z; f[7] = (half_t)b.w;
            wb[gt][kt] = f;
        }
        const float* phh = w_hh + grow * 64 + q * 8;
        #pragma unroll
        for (int kt = 0; kt < 2; ++kt) {
            const float4 a = *(const float4*)(phh + kt * 32);
            const float4 b = *(const float4*)(phh + kt * 32 + 4);
            v8h f;
            f[0] = (half_t)a.x; f[1] = (half_t)a.y; f[2] = (half_t)a.z; f[3] = (half_t)a.w;
            f[4] = (half_t)b.x; f[5] = (half_t)b.y; f[6] = (half_t)b.z; f[7] = (half_t)b.w;
            wb[gt][4 + kt] = f;
        }
        bias[gt] = b_ih[grow] + b_hh[grow];
    }

    float c[R], hcur[R];
    #pragma unroll
    for (int r = 0; r < R; ++r) { c[r] = 0.f; hcur[r] = 0.f; }

    const long t0 = rev ? (TT - 1) : 0;
    const long stride = rev ? -128 : 128;  // elements per time step

    const float*  xp32 = IN_F32 ? (const float*)in_v + (((size_t)(b0 + rowc)) * TT + t0) * 128 + q * 8 : nullptr;
    const half_t* xp16 = IN_F32 ? nullptr : (const half_t*)in_v + (((size_t)(b0 + rowc)) * TT + t0) * 128 + q * 8;

    half_t* op[R];
    if constexpr (WRITE_SEQ) {
        #pragma unroll
        for (int r = 0; r < R; ++r)
            op[r] = out_seq + (((size_t)(b0 + r)) * TT + t0) * 128 + col_off + j;
    }

    auto load_x = [&](v8h* dst) {
        if constexpr (IN_F32) {
            #pragma unroll
            for (int kt = 0; kt < 4; ++kt) {
                const float4 a = *(const float4*)(xp32 + kt * 32);
                const float4 b = *(const float4*)(xp32 + kt * 32 + 4);
                v8h f;
                f[0] = (half_t)a.x; f[1] = (half_t)a.y; f[2] = (half_t)a.z; f[3] = (half_t)a.w;
                f[4] = (half_t)b.x; f[5] = (half_t)b.y; f[6] = (half_t)b.z; f[7] = (half_t)b.w;
                dst[kt] = f;
            }
        } else {
            #pragma unroll
            for (int kt = 0; kt < 4; ++kt) dst[kt] = *(const v8h*)(xp16 + kt * 32);
        }
    };

    // prologue: x for tt=0
    v8h xf[4];
    load_x(xf);
    if constexpr (IN_F32) xp32 += stride; else xp16 += stride;

    barrier_lds_only();  // hs zero-init visible

    for (int tt = 0; tt < TT; ++tt) {
        const int p = tt & 1;

        // prefetch next x (stays in flight across the barrier below)
        v8h xn[4];
        if (tt + 1 < TT) {
            load_x(xn);
            if constexpr (IN_F32) xp32 += stride; else xp16 += stride;
        }

        // h A-fragments: m = n16, k = kh*32 + q*8 + e
        const v8h hf0 = *(const v8h*)&hs[p][n16][q * 8];
        const v8h hf1 = *(const v8h*)&hs[p][n16][32 + q * 8];

        v4f acc[4];
        #pragma unroll
        for (int gt = 0; gt < 4; ++gt) {
            v4f a = {bias[gt], bias[gt], bias[gt], bias[gt]};
            a = __builtin_amdgcn_mfma_f32_16x16x32_f16(xf[0], wb[gt][0], a, 0, 0, 0);
            a = __builtin_amdgcn_mfma_f32_16x16x32_f16(xf[1], wb[gt][1], a, 0, 0, 0);
            a = __builtin_amdgcn_mfma_f32_16x16x32_f16(xf[2], wb[gt][2], a, 0, 0, 0);
            a = __builtin_amdgcn_mfma_f32_16x16x32_f16(xf[3], wb[gt][3], a, 0, 0, 0);
            a = __builtin_amdgcn_mfma_f32_16x16x32_f16(hf0,   wb[gt][4], a, 0, 0, 0);
            a = __builtin_amdgcn_mfma_f32_16x16x32_f16(hf1,   wb[gt][5], a, 0, 0, 0);
            acc[gt] = a;
        }

        if (q == 0) {
            #pragma unroll
            for (int r = 0; r < R; ++r) {
                const float iv = sigf(acc[0][r]);
                const float fv = sigf(acc[1][r]);
                const float gv = tanhfast(acc[2][r]);
                const float ov = sigf(acc[3][r]);
                c[r] = fv * c[r] + iv * gv;
                hcur[r] = ov * tanhfast(c[r]);
                hs[p ^ 1][r][j] = (half_t)hcur[r];
                if constexpr (WRITE_SEQ) {
                    *op[r] = (half_t)hcur[r];
                    op[r] += stride;
                }
            }
        }

        barrier_lds_only();  // new h visible; x prefetch NOT drained

        #pragma unroll
        for (int kt = 0; kt < 4; ++kt) xf[kt] = xn[kt];  // last iter copies dead values
    }

    if constexpr (WRITE_LAST) {
        if (q == 0) {
            #pragma unroll
            for (int r = 0; r < R; ++r) out_last[((size_t)(b0 + r)) * 64 + j] = hcur[r];
        }
    }
}

// ---------------- fp32 -> fp16 pre-convert (x) ----------------
__global__ __launch_bounds__(256)
void cvt_f32_f16(const float* __restrict__ in, half_t* __restrict__ out)
{
    const size_t i = ((size_t)blockIdx.x * 256 + threadIdx.x) * 8;
    const float4 a = *(const float4*)(in + i);
    const float4 b = *(const float4*)(in + i + 4);
    v8h f;
    f[0] = (half_t)a.x; f[1] = (half_t)a.y; f[2] = (half_t)a.z; f[3] = (half_t)a.w;
    f[4] = (half_t)b.x; f[5] = (half_t)b.y; f[6] = (half_t)b.z; f[7] = (half_t)b.w;
    *(v8h*)(out + i) = f;
}

// ---------------- Layer 2 backward (single step from zero state) + FC ----------------
__global__ __launch_bounds__(256)
void l2bwd_fc(const half_t* __restrict__ in, const float* __restrict__ w_ih,
              const float* __restrict__ b_ih, const float* __restrict__ b_hh,
              const float* __restrict__ hlast, const float* __restrict__ fc_w,
              const float* __restrict__ fc_b, float* __restrict__ out)
{
    const int b = blockIdx.x;
    const int g = threadIdx.x;
    __shared__ float gpre[256];
    __shared__ float hb[64];

    float acc = b_ih[3 * 256 + g] + b_hh[3 * 256 + g];
    const float* wp = w_ih + ((size_t)(3 * 256 + g)) * 128;
    const half_t* xp = in + ((size_t)b * TT + (TT - 1)) * 128;
    #pragma unroll
    for (int k = 0; k < 128; k += 8) {
        const float4 w0 = *(const float4*)(wp + k);
        const float4 w1 = *(const float4*)(wp + k + 4);
        const v8h xv = *(const v8h*)(xp + k);
        acc = fmaf(w0.x, (float)xv[0], acc); acc = fmaf(w0.y, (float)xv[1], acc);
        acc = fmaf(w0.z, (float)xv[2], acc); acc = fmaf(w0.w, (float)xv[3], acc);
        acc = fmaf(w1.x, (float)xv[4], acc); acc = fmaf(w1.y, (float)xv[5], acc);
        acc = fmaf(w1.z, (float)xv[6], acc); acc = fmaf(w1.w, (float)xv[7], acc);
    }
    gpre[g] = acc;
    __syncthreads();

    if (g < 64) {
        const float i  = sigf(gpre[g]);
        const float gg = tanhfast(gpre[128 + g]);
        const float o  = sigf(gpre[192 + g]);
        const float cc = i * gg;
        hb[g] = o * tanhfast(cc);
    }
    __syncthreads();

    if (g < 64) {
        float p = fc_w[g] * hlast[(size_t)b * 64 + g] + fc_w[64 + g] * hb[g];
        #pragma unroll
        for (int off = 32; off > 0; off >>= 1) p += __shfl_down(p, off);
        if (g == 0) out[b] = p + fc_b[0];
    }
}

extern "C" void kernel_launch(void* const* d_in, const int* in_sizes, int n_in,
                              void* d_out, int out_size, void* d_ws, size_t ws_size,
                              hipStream_t stream)
{
    const float* x    = (const float*)d_in[0];
    const float* w_ih = (const float*)d_in[1];
    const float* w_hh = (const float*)d_in[2];
    const float* b_ih = (const float*)d_in[3];
    const float* b_hh = (const float*)d_in[4];
    const float* fc_w = (const float*)d_in[5];
    const float* fc_b = (const float*)d_in[6];
    float* out = (float*)d_out;

    const size_t seq_bytes = (size_t)BB * TT * 128 * sizeof(half_t);  // 128 MiB
    const size_t hlast_bytes = (size_t)BB * 64 * sizeof(float);

    if (ws_size >= 2 * seq_bytes + hlast_bytes) {
        // [ x16 128MB ][ out1 128MB ][ hlast ]
        half_t* x16  = (half_t*)d_ws;
        half_t* out1 = (half_t*)((char*)d_ws + seq_bytes);
        float*  hlast = (float*)((char*)d_ws + 2 * seq_bytes);

        cvt_f32_f16<<<(BB * TT * 128 / 8) / 256, 256, 0, stream>>>(x, x16);
        lstm_scan<2, false, true, false><<<dim3(BB / 2, 2), 256, 0, stream>>>(
            x16, w_ih, w_hh, b_ih, b_hh, 0, 1, out1, nullptr);
        lstm_scan<1, false, false, true><<<dim3(BB, 1), 256, 0, stream>>>(
            out1, w_ih, w_hh, b_ih, b_hh, 1, 0, nullptr, hlast);
        l2bwd_fc<<<BB, 256, 0, stream>>>(out1, w_ih, b_ih, b_hh, hlast, fc_w, fc_b, out);
    } else {
        // fallback: convert x in-kernel
        half_t* out1 = (half_t*)d_ws;
        float*  hlast = (float*)((char*)d_ws + seq_bytes);

        lstm_scan<2, true, true, false><<<dim3(BB / 2, 2), 256, 0, stream>>>(
            x, w_ih, w_hh, b_ih, b_hh, 0, 1, out1, nullptr);
        lstm_scan<1, false, false, true><<<dim3(BB, 1), 256, 0, stream>>>(
            out1, w_ih, w_hh, b_ih, b_hh, 1, 0, nullptr, hlast);
        l2bwd_fc<<<BB, 256, 0, stream>>>(out1, w_ih, b_ih, b_hh, hlast, fc_w, fc_b, out);
    }
}